// Round 3
// baseline (187.203 us; speedup 1.0000x reference)
//
#include <hip/hip_runtime.h>

// Volume rendering marcher: one wave (64 lanes) per 2 rays, 4 samples/lane/ray.
// S = 256, N = 32768.
//
// R1: libm -> native v_exp/v_rcp (t==1: m = 1/(1+e^x)).
// R2 (this round): latency hiding — 2 independent rays per wave, all global
// loads issued before the serial exp->scan chain, branchless scan.

__device__ __forceinline__ float one_minus_alpha_t1(float x) {
    // m = 1/(1 + e^x); x >= ~88 -> __expf = inf -> rcp = 0 (correct limit).
    return __builtin_amdgcn_rcpf(1.0f + __expf(x));
}

__device__ __forceinline__ float one_minus_alpha_gen(float x, float t) {
    // m = exp(-t * softplus(x)), stable softplus with native exp/log.
    float sp = fmaxf(x, 0.0f) + __logf(1.0f + __expf(-fabsf(x)));
    return __expf(-sp * t);
}

__global__ __launch_bounds__(256) void march_kernel(
    const float* __restrict__ density,   // [N,256]
    const float* __restrict__ shift,     // [256]
    const float* __restrict__ rgb,       // [N,256,3]
    const float* __restrict__ bg,        // [3]
    const int*   __restrict__ interval_p,
    float* __restrict__ out_rgb,         // [N,3]
    float* __restrict__ out_weights,     // [N,256]
    float* __restrict__ out_alast,       // [N]
    int n_rays)
{
    const int wave = threadIdx.x >> 6;
    const int lane = threadIdx.x & 63;
    const int ray0 = (blockIdx.x * 4 + wave) * 2;   // this wave's 2 rays
    if (ray0 >= n_rays) return;

    const float t = (float)(*interval_p);
    const bool t_is_one = (t == 1.0f);   // wave-uniform

    // ---- issue ALL global loads up front (overlap latency with compute) ----
    const float4 s4 = *reinterpret_cast<const float4*>(shift + lane * 4);

    float4 d4[2], r0[2], r1[2], r2[2];
    #pragma unroll
    for (int r = 0; r < 2; ++r) {
        const size_t ray = (size_t)(ray0 + r);
        d4[r] = *reinterpret_cast<const float4*>(density + ray * 256 + lane * 4);
        const float* rp = rgb + ray * 768 + lane * 12;
        r0[r] = *reinterpret_cast<const float4*>(rp);
        r1[r] = *reinterpret_cast<const float4*>(rp + 4);
        r2[r] = *reinterpret_cast<const float4*>(rp + 8);
    }
    const float bg0 = bg[0], bg1 = bg[1], bg2 = bg[2];

    // ---- two independent chains, unrolled & interleaved by the compiler ----
    #pragma unroll
    for (int r = 0; r < 2; ++r) {
        const size_t ray = (size_t)(ray0 + r);

        const float x0 = d4[r].x + s4.x;
        const float x1 = d4[r].y + s4.y;
        const float x2 = d4[r].z + s4.z;
        const float x3 = d4[r].w + s4.w;

        float m0, m1, m2, m3;
        if (t_is_one) {
            m0 = one_minus_alpha_t1(x0);
            m1 = one_minus_alpha_t1(x1);
            m2 = one_minus_alpha_t1(x2);
            m3 = one_minus_alpha_t1(x3);
        } else {
            m0 = one_minus_alpha_gen(x0, t);
            m1 = one_minus_alpha_gen(x1, t);
            m2 = one_minus_alpha_gen(x2, t);
            m3 = one_minus_alpha_gen(x3, t);
        }

        const float a0 = 1.0f - m0;
        const float a1 = 1.0f - m1;
        const float a2 = 1.0f - m2;
        const float a3 = 1.0f - m3;

        // local prefix products over this lane's 4 samples
        const float p1 = m0;
        const float p2 = p1 * m1;
        const float p3 = p2 * m2;
        const float p4 = p3 * m3;

        // wave-wide inclusive product scan (branchless Hillis-Steele)
        float incl = p4;
        #pragma unroll
        for (int off = 1; off < 64; off <<= 1) {
            float v = __shfl_up(incl, off, 64);
            incl *= (lane >= off) ? v : 1.0f;
        }
        float excl = __shfl_up(incl, 1, 64);
        excl = (lane == 0) ? 1.0f : excl;

        const float w0 = excl * a0;
        const float w1 = excl * p1 * a1;
        const float w2 = excl * p2 * a2;
        const float w3 = excl * p3 * a3;

        *reinterpret_cast<float4*>(out_weights + ray * 256 + lane * 4) =
            make_float4(w0, w1, w2, w3);

        const float T_last = __shfl(incl, 63, 64);

        // rgb weighted sum; lane's 12 floats:
        //  s0: r0.x r0.y r0.z | s1: r0.w r1.x r1.y | s2: r1.z r1.w r2.x | s3: r2.y r2.z r2.w
        float cr = w0 * r0[r].x + w1 * r0[r].w + w2 * r1[r].z + w3 * r2[r].y;
        float cg = w0 * r0[r].y + w1 * r1[r].x + w2 * r1[r].w + w3 * r2[r].z;
        float cb = w0 * r0[r].z + w1 * r1[r].y + w2 * r2[r].x + w3 * r2[r].w;

        #pragma unroll
        for (int off = 32; off >= 1; off >>= 1) {
            cr += __shfl_xor(cr, off, 64);
            cg += __shfl_xor(cg, off, 64);
            cb += __shfl_xor(cb, off, 64);
        }

        if (lane == 0) {
            out_rgb[ray * 3 + 0] = cr + T_last * bg0;
            out_rgb[ray * 3 + 1] = cg + T_last * bg1;
            out_rgb[ray * 3 + 2] = cb + T_last * bg2;
            out_alast[ray] = T_last;
        }
    }
}

extern "C" void kernel_launch(void* const* d_in, const int* in_sizes, int n_in,
                              void* d_out, int out_size, void* d_ws, size_t ws_size,
                              hipStream_t stream) {
    const float* density  = (const float*)d_in[0];
    const float* shift    = (const float*)d_in[1];
    const float* rgb      = (const float*)d_in[2];
    const float* bg       = (const float*)d_in[3];
    const int*   interval = (const int*)d_in[4];

    const int n_rays = in_sizes[0] / 256;   // 32768

    float* out = (float*)d_out;
    float* out_rgb     = out;                           // N*3
    float* out_weights = out + (size_t)n_rays * 3;      // N*256
    float* out_alast   = out + (size_t)n_rays * 3 + (size_t)n_rays * 256;  // N

    // 256 threads = 4 waves/block, 2 rays/wave -> 8 rays/block
    const int rays_per_block = 8;
    const int grid = (n_rays + rays_per_block - 1) / rays_per_block;

    march_kernel<<<grid, 256, 0, stream>>>(
        density, shift, rgb, bg, interval,
        out_rgb, out_weights, out_alast, n_rays);
}

// Round 5
// 186.102 us; speedup vs baseline: 1.0059x; 1.0059x over previous
//
#include <hip/hip_runtime.h>

// Volume rendering marcher: one wave (64 lanes) per 2 rays, 4 samples/lane/ray.
// S = 256, N = 32768.
//
// R1: libm -> native v_exp/v_rcp (t==1: m = 1/(1+e^x)).
// R2: 2 rays/wave, loads hoisted.
// R3/R4 (resubmit — R3 bench was an infra failure): ALL cross-lane ops via DPP
// (pure VALU) — zero ds_bpermute.
//   scan: row_shr:1/2/4/8 + row_bcast:15(0xa) + row_bcast:31(0xc)
//   exclusive shift: wave_shr:1 (lane 0 keeps identity via old-value)
//   reduction: same DPP scan, total lands in lane 63; lane 63 is the writer.

template <int CTRL, int ROW_MASK>
__device__ __forceinline__ float dpp_mov_f(float old_v, float src) {
    int o = __builtin_bit_cast(int, old_v);
    int s = __builtin_bit_cast(int, src);
    int r = __builtin_amdgcn_update_dpp(o, s, CTRL, ROW_MASK, 0xf, false);
    return __builtin_bit_cast(float, r);
}

// Inclusive product scan across 64 lanes (pure VALU DPP).
__device__ __forceinline__ float wave_incl_prod(float v) {
    v *= dpp_mov_f<0x111, 0xf>(1.0f, v);  // row_shr:1
    v *= dpp_mov_f<0x112, 0xf>(1.0f, v);  // row_shr:2
    v *= dpp_mov_f<0x114, 0xf>(1.0f, v);  // row_shr:4
    v *= dpp_mov_f<0x118, 0xf>(1.0f, v);  // row_shr:8
    v *= dpp_mov_f<0x142, 0xa>(1.0f, v);  // row_bcast:15 -> rows 1,3
    v *= dpp_mov_f<0x143, 0xc>(1.0f, v);  // row_bcast:31 -> rows 2,3
    return v;
}

// Inclusive sum scan; lane 63 ends with the full-wave total.
__device__ __forceinline__ float wave_sum_to_last(float v) {
    v += dpp_mov_f<0x111, 0xf>(0.0f, v);
    v += dpp_mov_f<0x112, 0xf>(0.0f, v);
    v += dpp_mov_f<0x114, 0xf>(0.0f, v);
    v += dpp_mov_f<0x118, 0xf>(0.0f, v);
    v += dpp_mov_f<0x142, 0xa>(0.0f, v);
    v += dpp_mov_f<0x143, 0xc>(0.0f, v);
    return v;
}

__device__ __forceinline__ float one_minus_alpha_t1(float x) {
    // m = 1/(1 + e^x); x >= ~88 -> __expf = inf -> rcp = 0 (correct limit).
    return __builtin_amdgcn_rcpf(1.0f + __expf(x));
}

__device__ __forceinline__ float one_minus_alpha_gen(float x, float t) {
    // m = exp(-t * softplus(x)), stable softplus with native exp/log.
    float sp = fmaxf(x, 0.0f) + __logf(1.0f + __expf(-fabsf(x)));
    return __expf(-sp * t);
}

__global__ __launch_bounds__(256) void march_kernel(
    const float* __restrict__ density,   // [N,256]
    const float* __restrict__ shift,     // [256]
    const float* __restrict__ rgb,       // [N,256,3]
    const float* __restrict__ bg,        // [3]
    const int*   __restrict__ interval_p,
    float* __restrict__ out_rgb,         // [N,3]
    float* __restrict__ out_weights,     // [N,256]
    float* __restrict__ out_alast,       // [N]
    int n_rays)
{
    const int wave = threadIdx.x >> 6;
    const int lane = threadIdx.x & 63;
    const int ray0 = (blockIdx.x * 4 + wave) * 2;   // this wave's 2 rays
    if (ray0 >= n_rays) return;

    const float t = (float)(*interval_p);
    const bool t_is_one = (t == 1.0f);   // wave-uniform

    // ---- issue ALL global loads up front ----
    const float4 s4 = *reinterpret_cast<const float4*>(shift + lane * 4);

    float4 d4[2], r0[2], r1[2], r2[2];
    #pragma unroll
    for (int r = 0; r < 2; ++r) {
        const size_t ray = (size_t)(ray0 + r);
        d4[r] = *reinterpret_cast<const float4*>(density + ray * 256 + lane * 4);
        const float* rp = rgb + ray * 768 + lane * 12;
        r0[r] = *reinterpret_cast<const float4*>(rp);
        r1[r] = *reinterpret_cast<const float4*>(rp + 4);
        r2[r] = *reinterpret_cast<const float4*>(rp + 8);
    }
    const float bg0 = bg[0], bg1 = bg[1], bg2 = bg[2];

    #pragma unroll
    for (int r = 0; r < 2; ++r) {
        const size_t ray = (size_t)(ray0 + r);

        const float x0 = d4[r].x + s4.x;
        const float x1 = d4[r].y + s4.y;
        const float x2 = d4[r].z + s4.z;
        const float x3 = d4[r].w + s4.w;

        float m0, m1, m2, m3;
        if (t_is_one) {
            m0 = one_minus_alpha_t1(x0);
            m1 = one_minus_alpha_t1(x1);
            m2 = one_minus_alpha_t1(x2);
            m3 = one_minus_alpha_t1(x3);
        } else {
            m0 = one_minus_alpha_gen(x0, t);
            m1 = one_minus_alpha_gen(x1, t);
            m2 = one_minus_alpha_gen(x2, t);
            m3 = one_minus_alpha_gen(x3, t);
        }

        const float a0 = 1.0f - m0;
        const float a1 = 1.0f - m1;
        const float a2 = 1.0f - m2;
        const float a3 = 1.0f - m3;

        // local prefix products over this lane's 4 samples
        const float p1 = m0;
        const float p2 = p1 * m1;
        const float p3 = p2 * m2;
        const float p4 = p3 * m3;

        // wave-wide inclusive product scan of per-lane totals (pure DPP)
        const float incl = wave_incl_prod(p4);
        // exclusive: shift incl down one lane across the whole wave;
        // lane 0 keeps old = 1.0 (wave_shr:1 crosses row boundaries).
        const float excl = dpp_mov_f<0x138, 0xf>(1.0f, incl);

        const float w0 = excl * a0;
        const float w1 = excl * p1 * a1;
        const float w2 = excl * p2 * a2;
        const float w3 = excl * p3 * a3;

        *reinterpret_cast<float4*>(out_weights + ray * 256 + lane * 4) =
            make_float4(w0, w1, w2, w3);

        // rgb weighted sum; lane's 12 floats:
        //  s0: r0.x r0.y r0.z | s1: r0.w r1.x r1.y | s2: r1.z r1.w r2.x | s3: r2.y r2.z r2.w
        float cr = w0 * r0[r].x + w1 * r0[r].w + w2 * r1[r].z + w3 * r2[r].y;
        float cg = w0 * r0[r].y + w1 * r1[r].x + w2 * r1[r].w + w3 * r2[r].z;
        float cb = w0 * r0[r].z + w1 * r1[r].y + w2 * r2[r].x + w3 * r2[r].w;

        // DPP sum-scan: totals land in lane 63 (which also holds T_last = incl)
        cr = wave_sum_to_last(cr);
        cg = wave_sum_to_last(cg);
        cb = wave_sum_to_last(cb);

        if (lane == 63) {
            const float T_last = incl;   // lane 63's inclusive product = total
            out_rgb[ray * 3 + 0] = cr + T_last * bg0;
            out_rgb[ray * 3 + 1] = cg + T_last * bg1;
            out_rgb[ray * 3 + 2] = cb + T_last * bg2;
            out_alast[ray] = T_last;
        }
    }
}

extern "C" void kernel_launch(void* const* d_in, const int* in_sizes, int n_in,
                              void* d_out, int out_size, void* d_ws, size_t ws_size,
                              hipStream_t stream) {
    const float* density  = (const float*)d_in[0];
    const float* shift    = (const float*)d_in[1];
    const float* rgb      = (const float*)d_in[2];
    const float* bg       = (const float*)d_in[3];
    const int*   interval = (const int*)d_in[4];

    const int n_rays = in_sizes[0] / 256;   // 32768

    float* out = (float*)d_out;
    float* out_rgb     = out;                           // N*3
    float* out_weights = out + (size_t)n_rays * 3;      // N*256
    float* out_alast   = out + (size_t)n_rays * 3 + (size_t)n_rays * 256;  // N

    // 256 threads = 4 waves/block, 2 rays/wave -> 8 rays/block
    const int rays_per_block = 8;
    const int grid = (n_rays + rays_per_block - 1) / rays_per_block;

    march_kernel<<<grid, 256, 0, stream>>>(
        density, shift, rgb, bg, interval,
        out_rgb, out_weights, out_alast, n_rays);
}